// Round 1
// baseline (894.149 us; speedup 1.0000x reference)
//
#include <hip/hip_runtime.h>
#include <cstddef>
#include <math.h>

#define BB 64
#define DD 2048
#define HH 2048
#define BD (BB*DD)   // 131072

// ---------------------------------------------------------------------------
// Split-K GEMM: part[ks] = A[64 x K] * W[K x N] over k-chunk ks.
// grid = (N/64, KS); block = 256. Each thread: one column, 16 rows.
// Deterministic: each split writes its own partial buffer (no atomics).
// ---------------------------------------------------------------------------
__device__ __forceinline__ void gemm_body(
    const float* __restrict__ A, const float* __restrict__ W,
    float* __restrict__ part, int K, int N, int kc)
{
    int tx = threadIdx.x & 63;
    int ty = threadIdx.x >> 6;            // 0..3 -> rows ty*16 .. ty*16+15
    int c  = blockIdx.x * 64 + tx;
    int k0 = blockIdx.y * kc;

    float acc[16];
#pragma unroll
    for (int r = 0; r < 16; ++r) acc[r] = 0.f;

    for (int k = k0; k < k0 + kc; k += 4) {
        float4 av[16];
#pragma unroll
        for (int r = 0; r < 16; ++r)
            av[r] = *(const float4*)&A[(size_t)(ty * 16 + r) * K + k];
#pragma unroll
        for (int j = 0; j < 4; ++j) {
            float w = W[(size_t)(k + j) * N + c];
#pragma unroll
            for (int r = 0; r < 16; ++r) {
                float a = (j == 0) ? av[r].x : (j == 1) ? av[r].y
                         : (j == 2) ? av[r].z : av[r].w;
                acc[r] = fmaf(a, w, acc[r]);
            }
        }
    }

    float* P = part + (size_t)blockIdx.y * ((size_t)BB * N);
#pragma unroll
    for (int r = 0; r < 16; ++r)
        P[(size_t)(ty * 16 + r) * N + c] = acc[r];
}

__global__ __launch_bounds__(256) void gemm_splitk(
    const float* __restrict__ A, const float* __restrict__ W,
    float* __restrict__ part, int K, int N, int kc)
{
    gemm_body(A, W, part, K, N, kc);
}

// 3 independent GEMMs fused via blockIdx.z (z @ Wk / Wv / Wq)
__global__ __launch_bounds__(256) void gemm_splitk_z3(
    const float* __restrict__ A,
    const float* __restrict__ W0, const float* __restrict__ W1,
    const float* __restrict__ W2,
    float* __restrict__ p0, float* __restrict__ p1, float* __restrict__ p2,
    int K, int N, int kc)
{
    const float* W = (blockIdx.z == 0) ? W0 : (blockIdx.z == 1) ? W1 : W2;
    float*       P = (blockIdx.z == 0) ? p0 : (blockIdx.z == 1) ? p1 : p2;
    gemm_body(A, W, P, K, N, kc);
}

// ---------------------------------------------------------------------------
// Epilogue: out[i] = act( sum_ks part[ks][i] + bias[i & (N-1)] )
// act: 0 = none, 1 = tanh, 2 = exp
// ---------------------------------------------------------------------------
__global__ __launch_bounds__(256) void epilogue(
    const float* __restrict__ part, const float* __restrict__ bias,
    float* __restrict__ out, int N, int act, int total, int KS)
{
    int i = blockIdx.x * 256 + threadIdx.x;
    if (i >= total) return;
    float s = bias[i & (N - 1)];
    for (int ks = 0; ks < KS; ++ks) s += part[(size_t)ks * total + i];
    if (act == 1)      s = tanhf(s);
    else if (act == 2) s = expf(s);
    out[i] = s;
}

// dq[i] = q[i] * (sum_ks part[ks][i] + bq[i & (N-1)])
__global__ __launch_bounds__(256) void epilogue_dq(
    const float* __restrict__ part, const float* __restrict__ bias,
    const float* __restrict__ q, float* __restrict__ dq,
    int N, int total, int KS)
{
    int i = blockIdx.x * 256 + threadIdx.x;
    if (i >= total) return;
    float s = bias[i & (N - 1)];
    for (int ks = 0; ks < KS; ++ks) s += part[(size_t)ks * total + i];
    dq[i] = q[i] * s;
}

// ---------------------------------------------------------------------------
// Per-batch reductions: a[b] = sum_e q*dK ; da[b] = a[b] + sum_e dq*K
// grid = 64 (one block per b), block = 256
// ---------------------------------------------------------------------------
__global__ __launch_bounds__(256) void reduce_a_da(
    const float* __restrict__ q, const float* __restrict__ dK,
    const float* __restrict__ dq, const float* __restrict__ Kin,
    float* __restrict__ a_ws, float* __restrict__ da_out)
{
    int b = blockIdx.x;
    int t = threadIdx.x;
    const float* qb  = q   + (size_t)b * DD;
    const float* dKb = dK  + (size_t)b * DD;
    const float* dqb = dq  + (size_t)b * DD;
    const float* Kb  = Kin + (size_t)b * DD;

    float s1 = 0.f, s2 = 0.f;
    for (int i = t; i < DD; i += 256) {
        s1 = fmaf(qb[i],  dKb[i], s1);
        s2 = fmaf(dqb[i], Kb[i],  s2);
    }
#pragma unroll
    for (int off = 32; off; off >>= 1) {
        s1 += __shfl_down(s1, off);
        s2 += __shfl_down(s2, off);
    }
    __shared__ float r1[4], r2[4];
    if ((t & 63) == 0) { r1[t >> 6] = s1; r2[t >> 6] = s2; }
    __syncthreads();
    if (t == 0) {
        float a  = r1[0] + r1[1] + r1[2] + r1[3];
        float k2 = r2[0] + r2[1] + r2[2] + r2[3];
        a_ws[b]  = a;
        da_out[b] = a + k2;
    }
}

// ---------------------------------------------------------------------------
// Fused dV / dc:
//   dV[b,d,e] = v[b,d] * dK[b,e]
//   dc[b,d]   = v[b,d] * a[b] + sum_e V[b,d,e] * dq[b,e]
// grid = B*D (one block per output row), block = 256, float4 streams.
// ---------------------------------------------------------------------------
__global__ __launch_bounds__(256) void fused_dv_dc(
    const float* __restrict__ V, const float* __restrict__ v,
    const float* __restrict__ dK, const float* __restrict__ dq,
    const float* __restrict__ a, float* __restrict__ dV,
    float* __restrict__ dc)
{
    int bd = blockIdx.x;              // b*D + d
    int b  = bd >> 11;                // D = 2048
    size_t rowoff = (size_t)bd * DD;

    const float4* V4  = (const float4*)(V  + rowoff);
    float4*       dV4 = (float4*)(dV + rowoff);
    const float4* dK4 = (const float4*)(dK + ((size_t)b << 11));
    const float4* dq4 = (const float4*)(dq + ((size_t)b << 11));

    float vbd = v[bd];
    int t = threadIdx.x;
    float accl = 0.f;

#pragma unroll
    for (int i = 0; i < 2; ++i) {
        int idx = i * 256 + t;
        float4 Vv  = V4[idx];
        float4 dqv = dq4[idx];
        float4 dKv = dK4[idx];
        accl += Vv.x * dqv.x + Vv.y * dqv.y + Vv.z * dqv.z + Vv.w * dqv.w;
        float4 o;
        o.x = vbd * dKv.x; o.y = vbd * dKv.y;
        o.z = vbd * dKv.z; o.w = vbd * dKv.w;
        dV4[idx] = o;
    }

#pragma unroll
    for (int off = 32; off; off >>= 1) accl += __shfl_down(accl, off);
    __shared__ float red[4];
    if ((t & 63) == 0) red[t >> 6] = accl;
    __syncthreads();
    if (t == 0) dc[bd] = vbd * a[b] + red[0] + red[1] + red[2] + red[3];
}

// ---------------------------------------------------------------------------
extern "C" void kernel_launch(void* const* d_in, const int* in_sizes, int n_in,
                              void* d_out, int out_size, void* d_ws, size_t ws_size,
                              hipStream_t stream)
{
    // inputs: 0 t, 1 z, 2 K, 3 V, 4 Wq, 5 bq, 6 Wk, 7 bk, 8 Wv, 9 bv,
    //         10 W1, 11 b1, 12 W2, 13 b2
    const float* z   = (const float*)d_in[1];
    const float* Kin = (const float*)d_in[2];
    const float* Vin = (const float*)d_in[3];
    const float* Wq  = (const float*)d_in[4];
    const float* bq  = (const float*)d_in[5];
    const float* Wk  = (const float*)d_in[6];
    const float* bk  = (const float*)d_in[7];
    const float* Wv  = (const float*)d_in[8];
    const float* bv  = (const float*)d_in[9];
    const float* W1  = (const float*)d_in[10];
    const float* b1  = (const float*)d_in[11];
    const float* W2  = (const float*)d_in[12];
    const float* b2  = (const float*)d_in[13];

    float* out   = (float*)d_out;
    float* o_dz  = out;                 // [B,D]
    float* o_da  = out + BD;            // [B,1] (64)
    float* o_dc  = out + BD + BB;       // [B,D]
    float* o_dK  = out + 2 * BD + BB;   // [B,D]
    float* o_dV  = out + 3 * BD + BB;   // [B,D,D]

    float* ws    = (float*)d_ws;
    float* ws_h  = ws;                  // [B,H]
    float* ws_v  = ws + BD;             // [B,D]
    float* ws_q  = ws + 2 * BD;         // [B,D]
    float* ws_dq = ws + 3 * BD;         // [B,D]
    float* ws_a  = ws + 4 * BD;         // [B] (64)
    float* part  = ws + 4 * BD + 64;    // 3 * KS * B*D partial buffers

    // pick the largest split factor the workspace can hold
    int KS = 8;
    while (KS > 1 &&
           ((size_t)(4 * BD + 64) + 3ull * KS * BD) * 4ull > ws_size)
        KS >>= 1;
    int kc = DD / KS;

    float* p0 = part;
    float* p1 = part + (size_t)KS * BD;
    float* p2 = part + 2 * (size_t)KS * BD;

    dim3 blk(256);
    dim3 gG(DD / 64, KS);      // GEMM grid
    dim3 gG3(DD / 64, KS, 3);
    dim3 gE(BD / 256);         // 512 blocks

    // 1) h = tanh(z @ W1 + b1)
    gemm_splitk<<<gG, blk, 0, stream>>>(z, W1, p0, DD, HH, kc);
    epilogue<<<gE, blk, 0, stream>>>(p0, b1, ws_h, HH, 1, BD, KS);

    // 2) dz = h @ W2 + b2
    gemm_splitk<<<gG, blk, 0, stream>>>(ws_h, W2, p0, HH, DD, kc);
    epilogue<<<gE, blk, 0, stream>>>(p0, b2, o_dz, DD, 0, BD, KS);

    // 3) dK = exp(z@Wk+bk); v = z@Wv+bv; q = exp(z@Wq+bq)
    gemm_splitk_z3<<<gG3, blk, 0, stream>>>(z, Wk, Wv, Wq, p0, p1, p2, DD, DD, kc);
    epilogue<<<gE, blk, 0, stream>>>(p0, bk, o_dK, DD, 2, BD, KS);
    epilogue<<<gE, blk, 0, stream>>>(p1, bv, ws_v, DD, 0, BD, KS);
    epilogue<<<gE, blk, 0, stream>>>(p2, bq, ws_q, DD, 2, BD, KS);

    // 4) dq = q * (dz @ Wq + bq)
    gemm_splitk<<<gG, blk, 0, stream>>>(o_dz, Wq, p0, DD, DD, kc);
    epilogue_dq<<<gE, blk, 0, stream>>>(p0, bq, ws_q, ws_dq, DD, BD, KS);

    // 5) a[b] = q . dK ; da[b] = a + dq . K
    reduce_a_da<<<dim3(BB), blk, 0, stream>>>(ws_q, o_dK, ws_dq, Kin, ws_a, o_da);

    // 6) dV = outer(v, dK); dc = v*a + V @ dq
    fused_dv_dc<<<dim3(BD), blk, 0, stream>>>(Vin, ws_v, o_dK, ws_dq, ws_a,
                                              o_dV, o_dc);
}

// Round 2
// 513.240 us; speedup vs baseline: 1.7422x; 1.7422x over previous
//
#include <hip/hip_runtime.h>
#include <cstddef>
#include <math.h>

#define BB 64
#define DD 2048
#define HH 2048
#define BD (BB*DD)   // 131072

// ---------------------------------------------------------------------------
// f32 LDS-tiled split-K GEMM.
//   out tile per block: MT rows x 64 cols, k-chunk kc per blockIdx.y split.
//   MT = 64 (A0 only) or 128 (rows 0-63 from A0, 64-127 from A1).
//   part layout: [KS][MT][2048]
// 256 threads: thread (i=t>>4, j=t&15) computes rows i*RT..i*RT+RT-1,
// cols 4j..4j+3, via LDS-staged A^T and W chunks (KC=32).
// ---------------------------------------------------------------------------
template<int MT>
__device__ __forceinline__ void gemm_body(
    const float* __restrict__ A0, const float* __restrict__ A1,
    const float* __restrict__ W, float* __restrict__ part, int kc)
{
    constexpr int KC = 32;
    constexpr int RT = MT / 16;          // 4 or 8 rows per thread
    __shared__ float As[KC][MT];         // A transposed: As[k][m]
    __shared__ float Ws[KC][64];

    const int t  = threadIdx.x;
    const int n0 = blockIdx.x * 64;
    const int k0 = blockIdx.y * kc;
    const int i  = t >> 4;               // 0..15
    const int j  = t & 15;               // 0..15

    float acc[RT][4];
#pragma unroll
    for (int r = 0; r < RT; ++r)
#pragma unroll
        for (int c = 0; c < 4; ++c) acc[r][c] = 0.f;

    for (int kk0 = 0; kk0 < kc; kk0 += KC) {
        // ---- stage W: 32 x 64 floats, 8 per thread, coalesced
        {
            int kk = t >> 3;
            int nn = (t & 7) << 3;
            const float* s = W + (size_t)(k0 + kk0 + kk) * DD + n0 + nn;
            *(float4*)&Ws[kk][nn]     = *(const float4*)s;
            *(float4*)&Ws[kk][nn + 4] = *(const float4*)(s + 4);
        }
        // ---- stage A (transposed into LDS)
        if constexpr (MT == 64) {
            int m  = t & 63;
            int kb = (t >> 6) << 3;      // 0,8,16,24
            const float* s = A0 + (size_t)m * DD + k0 + kk0 + kb;
            float4 a0 = *(const float4*)s;
            float4 a1 = *(const float4*)(s + 4);
            As[kb+0][m] = a0.x; As[kb+1][m] = a0.y;
            As[kb+2][m] = a0.z; As[kb+3][m] = a0.w;
            As[kb+4][m] = a1.x; As[kb+5][m] = a1.y;
            As[kb+6][m] = a1.z; As[kb+7][m] = a1.w;
        } else {
            int m  = t & 127;
            int kb = (t >> 7) << 4;      // 0 or 16
            const float* base = (m < 64) ? (A0 + (size_t)m * DD)
                                         : (A1 + (size_t)(m - 64) * DD);
            const float* s = base + k0 + kk0 + kb;
#pragma unroll
            for (int p = 0; p < 4; ++p) {
                float4 av = *(const float4*)(s + p * 4);
                As[kb+p*4+0][m] = av.x; As[kb+p*4+1][m] = av.y;
                As[kb+p*4+2][m] = av.z; As[kb+p*4+3][m] = av.w;
            }
        }
        __syncthreads();

#pragma unroll
        for (int kk = 0; kk < KC; ++kk) {
            float4 wv = *(float4*)&Ws[kk][j << 2];
#pragma unroll
            for (int rq = 0; rq < RT / 4; ++rq) {
                float4 av = *(float4*)&As[kk][i * RT + rq * 4];
                acc[rq*4+0][0] = fmaf(av.x, wv.x, acc[rq*4+0][0]);
                acc[rq*4+0][1] = fmaf(av.x, wv.y, acc[rq*4+0][1]);
                acc[rq*4+0][2] = fmaf(av.x, wv.z, acc[rq*4+0][2]);
                acc[rq*4+0][3] = fmaf(av.x, wv.w, acc[rq*4+0][3]);
                acc[rq*4+1][0] = fmaf(av.y, wv.x, acc[rq*4+1][0]);
                acc[rq*4+1][1] = fmaf(av.y, wv.y, acc[rq*4+1][1]);
                acc[rq*4+1][2] = fmaf(av.y, wv.z, acc[rq*4+1][2]);
                acc[rq*4+1][3] = fmaf(av.y, wv.w, acc[rq*4+1][3]);
                acc[rq*4+2][0] = fmaf(av.z, wv.x, acc[rq*4+2][0]);
                acc[rq*4+2][1] = fmaf(av.z, wv.y, acc[rq*4+2][1]);
                acc[rq*4+2][2] = fmaf(av.z, wv.z, acc[rq*4+2][2]);
                acc[rq*4+2][3] = fmaf(av.z, wv.w, acc[rq*4+2][3]);
                acc[rq*4+3][0] = fmaf(av.w, wv.x, acc[rq*4+3][0]);
                acc[rq*4+3][1] = fmaf(av.w, wv.y, acc[rq*4+3][1]);
                acc[rq*4+3][2] = fmaf(av.w, wv.z, acc[rq*4+3][2]);
                acc[rq*4+3][3] = fmaf(av.w, wv.w, acc[rq*4+3][3]);
            }
        }
        __syncthreads();
    }

    float* P = part + (size_t)blockIdx.y * MT * DD + n0 + (j << 2);
#pragma unroll
    for (int r = 0; r < RT; ++r) {
        *(float4*)&P[(size_t)(i * RT + r) * DD] =
            make_float4(acc[r][0], acc[r][1], acc[r][2], acc[r][3]);
    }
}

__global__ __launch_bounds__(256) void gemm64(
    const float* __restrict__ A, const float* __restrict__ W,
    float* __restrict__ part, int kc)
{
    gemm_body<64>(A, A, W, part, kc);
}

// two independent M=64 GEMMs sharing A (z @ Wk, z @ Wv)
__global__ __launch_bounds__(256) void gemm64_z2(
    const float* __restrict__ A,
    const float* __restrict__ W0, const float* __restrict__ W1,
    float* __restrict__ p0, float* __restrict__ p1, int kc)
{
    const float* W = blockIdx.z ? W1 : W0;
    float*       P = blockIdx.z ? p1 : p0;
    gemm_body<64>(A, A, W, P, kc);
}

// stacked [z; dz] @ Wq, M=128
__global__ __launch_bounds__(256) void gemm128(
    const float* __restrict__ A0, const float* __restrict__ A1,
    const float* __restrict__ W, float* __restrict__ part, int kc)
{
    gemm_body<128>(A0, A1, W, part, kc);
}

// ---------------------------------------------------------------------------
// Epilogues
// ---------------------------------------------------------------------------
// out = act(sum_ks part + bias); act: 0 none, 1 tanh
__global__ __launch_bounds__(256) void epilogue(
    const float* __restrict__ part, const float* __restrict__ bias,
    float* __restrict__ out, int act, int KS)
{
    int idx = blockIdx.x * 256 + threadIdx.x;
    float s = bias[idx & (DD - 1)];
    for (int ks = 0; ks < KS; ++ks) s += part[(size_t)ks * BD + idx];
    if (act == 1) s = tanhf(s);
    out[idx] = s;
}

// dK = exp(sum pk + bk); v = sum pv + bv
__global__ __launch_bounds__(256) void epilogue_kv(
    const float* __restrict__ pk, const float* __restrict__ pv,
    const float* __restrict__ bk, const float* __restrict__ bv,
    float* __restrict__ dKo, float* __restrict__ vo, int KS)
{
    int idx = blockIdx.x * 256 + threadIdx.x;
    int d = idx & (DD - 1);
    float sk = 0.f, sv = 0.f;
    for (int ks = 0; ks < KS; ++ks) {
        sk += pk[(size_t)ks * BD + idx];
        sv += pv[(size_t)ks * BD + idx];
    }
    dKo[idx] = expf(sk + bk[d]);
    vo[idx]  = sv + bv[d];
}

// pq: [KS][128][DD]; rows 0-63 = z@Wq (-> q), rows 64-127 = dz@Wq (-> dq)
__global__ __launch_bounds__(256) void epilogue_q_dq(
    const float* __restrict__ pq, const float* __restrict__ bq,
    float* __restrict__ qo, float* __restrict__ dqo, int KS)
{
    int idx = blockIdx.x * 256 + threadIdx.x;
    int b = idx >> 11, d = idx & (DD - 1);
    float sq = 0.f, sd = 0.f;
    for (int ks = 0; ks < KS; ++ks) {
        const float* P = pq + (size_t)ks * (128 * DD);
        sq += P[(size_t)b * DD + d];
        sd += P[(size_t)(b + 64) * DD + d];
    }
    float bb = bq[d];
    float qv = expf(sq + bb);
    qo[idx]  = qv;
    dqo[idx] = qv * (sd + bb);
}

// ---------------------------------------------------------------------------
// a[b] = q . dK ; da[b] = a[b] + dq . K     (one block per batch)
// ---------------------------------------------------------------------------
__global__ __launch_bounds__(256) void reduce_a_da(
    const float* __restrict__ q, const float* __restrict__ dK,
    const float* __restrict__ dq, const float* __restrict__ Kin,
    float* __restrict__ a_ws, float* __restrict__ da_out)
{
    int b = blockIdx.x;
    int t = threadIdx.x;
    const float* qb  = q   + (size_t)b * DD;
    const float* dKb = dK  + (size_t)b * DD;
    const float* dqb = dq  + (size_t)b * DD;
    const float* Kb  = Kin + (size_t)b * DD;

    float s1 = 0.f, s2 = 0.f;
    for (int i = t; i < DD; i += 256) {
        s1 = fmaf(qb[i],  dKb[i], s1);
        s2 = fmaf(dqb[i], Kb[i],  s2);
    }
#pragma unroll
    for (int off = 32; off; off >>= 1) {
        s1 += __shfl_down(s1, off);
        s2 += __shfl_down(s2, off);
    }
    __shared__ float r1[4], r2[4];
    if ((t & 63) == 0) { r1[t >> 6] = s1; r2[t >> 6] = s2; }
    __syncthreads();
    if (t == 0) {
        float a  = r1[0] + r1[1] + r1[2] + r1[3];
        float k2 = r2[0] + r2[1] + r2[2] + r2[3];
        a_ws[b]   = a;
        da_out[b] = a + k2;
    }
}

// ---------------------------------------------------------------------------
// Fused dV / dc, wave-per-row, dK/dq rows cached in registers.
//   grid = 64 batches x 32 chunks; block = 256 (4 waves x 16 rows each)
//   element mapping per lane: float4 u*256 + lane*4, u = 0..7 (coalesced)
// ---------------------------------------------------------------------------
__global__ __launch_bounds__(256) void fused_dv_dc(
    const float* __restrict__ V, const float* __restrict__ v,
    const float* __restrict__ dK, const float* __restrict__ dq,
    const float* __restrict__ a, float* __restrict__ dV,
    float* __restrict__ dc)
{
    int b     = blockIdx.x >> 5;
    int chunk = blockIdx.x & 31;
    int wave  = threadIdx.x >> 6;
    int lane  = threadIdx.x & 63;

    const float4* dK4 = (const float4*)(dK + ((size_t)b << 11));
    const float4* dq4 = (const float4*)(dq + ((size_t)b << 11));
    float4 dKr[8], dqr[8];
#pragma unroll
    for (int u = 0; u < 8; ++u) {
        dKr[u] = dK4[u * 64 + lane];
        dqr[u] = dq4[u * 64 + lane];
    }
    float ab = a[b];

    int row0 = chunk * 64 + wave * 16;
    for (int rr = 0; rr < 16; ++rr) {
        int row = row0 + rr;
        size_t off = ((size_t)((b << 11) | row)) << 11;
        const float4* V4  = (const float4*)(V  + off);
        float4*       dV4 = (float4*)(dV + off);

        float dot = 0.f;
        float vr = v[((size_t)b << 11) + row];
#pragma unroll
        for (int u = 0; u < 8; ++u) {
            float4 Vv = V4[u * 64 + lane];
            dot += Vv.x * dqr[u].x + Vv.y * dqr[u].y
                 + Vv.z * dqr[u].z + Vv.w * dqr[u].w;
        }
#pragma unroll
        for (int u = 0; u < 8; ++u) {
            float4 o;
            o.x = vr * dKr[u].x; o.y = vr * dKr[u].y;
            o.z = vr * dKr[u].z; o.w = vr * dKr[u].w;
            dV4[u * 64 + lane] = o;
        }
#pragma unroll
        for (int s = 32; s; s >>= 1) dot += __shfl_down(dot, s);
        if (lane == 0) dc[((size_t)b << 11) + row] = vr * ab + dot;
    }
}

// ---------------------------------------------------------------------------
extern "C" void kernel_launch(void* const* d_in, const int* in_sizes, int n_in,
                              void* d_out, int out_size, void* d_ws, size_t ws_size,
                              hipStream_t stream)
{
    // inputs: 0 t, 1 z, 2 K, 3 V, 4 Wq, 5 bq, 6 Wk, 7 bk, 8 Wv, 9 bv,
    //         10 W1, 11 b1, 12 W2, 13 b2
    const float* z   = (const float*)d_in[1];
    const float* Kin = (const float*)d_in[2];
    const float* Vin = (const float*)d_in[3];
    const float* Wq  = (const float*)d_in[4];
    const float* bq  = (const float*)d_in[5];
    const float* Wk  = (const float*)d_in[6];
    const float* bk  = (const float*)d_in[7];
    const float* Wv  = (const float*)d_in[8];
    const float* bv  = (const float*)d_in[9];
    const float* W1  = (const float*)d_in[10];
    const float* b1  = (const float*)d_in[11];
    const float* W2  = (const float*)d_in[12];
    const float* b2  = (const float*)d_in[13];

    float* out   = (float*)d_out;
    float* o_dz  = out;                 // [B,D]
    float* o_da  = out + BD;            // [B,1]
    float* o_dc  = out + BD + BB;       // [B,D]
    float* o_dK  = out + 2 * BD + BB;   // [B,D]
    float* o_dV  = out + 3 * BD + BB;   // [B,D,D]

    float* ws    = (float*)d_ws;
    float* ws_h  = ws;                  // [B,H]
    float* ws_v  = ws + BD;             // [B,D]
    float* ws_q  = ws + 2 * BD;         // [B,D]
    float* ws_dq = ws + 3 * BD;         // [B,D]
    float* ws_a  = ws + 4 * BD;         // [B]
    float* pool  = ws + 4 * BD + 64;    // 2 * KS * BD floats

    // largest split factor that fits the workspace (pool = 2*KS*BD floats)
    int KS = 16;
    while (KS > 1 &&
           ((size_t)(4 * BD + 64) + 2ull * KS * BD) * 4ull > ws_size)
        KS >>= 1;
    int kc = DD / KS;

    float* p0 = pool;                   // KS*BD
    float* p1 = pool + (size_t)KS * BD; // KS*BD   (p0..p1 span = pq for M=128)

    dim3 blk(256);
    dim3 gG(DD / 64, KS);
    dim3 gG2(DD / 64, KS, 2);
    dim3 gE(BD / 256);

    // 1) h = tanh(z @ W1 + b1)
    gemm64<<<gG, blk, 0, stream>>>(z, W1, p0, kc);
    epilogue<<<gE, blk, 0, stream>>>(p0, b1, ws_h, 1, KS);

    // 2) dz = h @ W2 + b2
    gemm64<<<gG, blk, 0, stream>>>(ws_h, W2, p0, kc);
    epilogue<<<gE, blk, 0, stream>>>(p0, b2, o_dz, 0, KS);

    // 3) dK = exp(z@Wk+bk); v = z@Wv+bv
    gemm64_z2<<<gG2, blk, 0, stream>>>(z, Wk, Wv, p0, p1, kc);
    epilogue_kv<<<gE, blk, 0, stream>>>(p0, p1, bk, bv, o_dK, ws_v, KS);

    // 4) [z; dz] @ Wq -> q = exp(.+bq), dq = q * (.+bq)
    gemm128<<<gG, blk, 0, stream>>>(z, o_dz, Wq, p0, kc);
    epilogue_q_dq<<<gE, blk, 0, stream>>>(p0, bq, ws_q, ws_dq, KS);

    // 5) a = q . dK ; da = a + dq . K
    reduce_a_da<<<dim3(BB), blk, 0, stream>>>(ws_q, o_dK, ws_dq, Kin, ws_a, o_da);

    // 6) dV = outer(v, dK); dc = v*a + V @ dq
    fused_dv_dc<<<dim3(BB * 32), blk, 0, stream>>>(Vin, ws_v, o_dK, ws_dq, ws_a,
                                                   o_dV, o_dc);
}

// Round 3
// 493.947 us; speedup vs baseline: 1.8102x; 1.0391x over previous
//
#include <hip/hip_runtime.h>
#include <cstddef>
#include <math.h>

#define BB 64
#define DD 2048
#define HH 2048
#define BD (BB*DD)   // 131072
#define WN (2048*2048)

typedef unsigned short u16;
typedef __attribute__((ext_vector_type(8))) short bf16x8;
typedef __attribute__((ext_vector_type(4))) float f32x4;
typedef __attribute__((ext_vector_type(4))) float f4;

__device__ __forceinline__ u16 f2b(float x) {
    union { float f; unsigned u; } v; v.f = x;
    unsigned r = v.u + 0x7FFFu + ((v.u >> 16) & 1u);
    return (u16)(r >> 16);
}

__device__ __forceinline__ void gload16(const void* g, void* l) {
    __builtin_amdgcn_global_load_lds(
        (__attribute__((address_space(1))) void*)g,
        (__attribute__((address_space(3))) void*)l, 16, 0, 0);
}

// ===========================================================================
// bf16 path
// ===========================================================================

// ---- convert 5 weights f32[k][n] -> bf16 transposed Wt[n][k], tiled 64x64
__global__ __launch_bounds__(256) void wconv(
    const float* __restrict__ W0, const float* __restrict__ W1,
    const float* __restrict__ W2, const float* __restrict__ W3,
    const float* __restrict__ W4, u16* __restrict__ wt)
{
    const float* W;
    switch (blockIdx.z) {
        case 0: W = W0; break; case 1: W = W1; break;
        case 2: W = W2; break; case 3: W = W3; break;
        default: W = W4; break;
    }
    u16* T = wt + (size_t)blockIdx.z * WN;

    __shared__ u16 tile[64][66];
    int k0 = blockIdx.x * 64, n0 = blockIdx.y * 64;
    int t = threadIdx.x;
    {   // read phase: coalesced rows of W
        int r = t >> 2, c0 = (t & 3) * 16;
        const float* src = W + (size_t)(k0 + r) * DD + n0 + c0;
#pragma unroll
        for (int q = 0; q < 4; ++q) {
            float4 f = *(const float4*)(src + q * 4);
            tile[r][c0 + q*4 + 0] = f2b(f.x);
            tile[r][c0 + q*4 + 1] = f2b(f.y);
            tile[r][c0 + q*4 + 2] = f2b(f.z);
            tile[r][c0 + q*4 + 3] = f2b(f.w);
        }
    }
    __syncthreads();
    {   // write phase: coalesced rows of Wt (= columns of W)
        int rn = t >> 2, ck = (t & 3) * 16;
        u16 o[16];
#pragma unroll
        for (int j = 0; j < 16; ++j) o[j] = tile[ck + j][rn];
        u16* dst = T + (size_t)(n0 + rn) * DD + k0 + ck;
        *(bf16x8*)dst       = *(bf16x8*)&o[0];
        *(bf16x8*)(dst + 8) = *(bf16x8*)&o[8];
    }
}

// ---- z f32 -> bf16
__global__ __launch_bounds__(256) void zconv(
    const float* __restrict__ z, u16* __restrict__ zb)
{
    int i = (blockIdx.x * 256 + threadIdx.x) * 4;
    float4 f = *(const float4*)&z[i];
    union { u16 u[4]; uint2 v; } o;
    o.u[0] = f2b(f.x); o.u[1] = f2b(f.y); o.u[2] = f2b(f.z); o.u[3] = f2b(f.w);
    *(uint2*)&zb[i] = o.v;
}

// ---- MFMA GEMM body: 64x64 tile, A[64][2048] bf16, Wt[n][k] bf16.
// P already offset for (split, mrow0); writes P[m][n] stride 2048.
__device__ __forceinline__ void gemm_bf16_body(
    const u16* __restrict__ A, const u16* __restrict__ Wt,
    float* __restrict__ P, int kc)
{
    __shared__ u16 Als[64 * 32];
    __shared__ u16 Wls[64 * 32];
    const int t = threadIdx.x, w = t >> 6, lane = t & 63;
    const int n0 = blockIdx.x * 64;
    const int k0 = blockIdx.y * kc;

    f32x4 acc[4];
#pragma unroll
    for (int mt = 0; mt < 4; ++mt) acc[mt] = (f32x4){0.f, 0.f, 0.f, 0.f};

    // staging addresses: wave w stages 16 rows of A and 16 rows of Wt
    const int srow = lane >> 2;          // 0..15
    const int sk   = (lane & 3) * 8;     // ushort offset (16B chunks)
    const u16* gA = A  + (size_t)(w * 16 + srow) * DD + k0 + sk;
    const u16* gW = Wt + (size_t)(n0 + w * 16 + srow) * DD + k0 + sk;
    u16* lA = &Als[w * 512];             // wave-uniform; HW adds lane*16B
    u16* lW = &Wls[w * 512];

    const int lane15 = lane & 15;
    const int k8 = (lane >> 4) * 8;

    for (int kk = 0; kk < kc; kk += 32) {
        gload16(gA, lA);
        gload16(gW, lW);
        gA += 32; gW += 32;
        __syncthreads();

        bf16x8 bfrag = *(const bf16x8*)&Wls[(w * 16 + lane15) * 32 + k8];
#pragma unroll
        for (int mt = 0; mt < 4; ++mt) {
            bf16x8 afrag = *(const bf16x8*)&Als[(mt * 16 + lane15) * 32 + k8];
            acc[mt] = __builtin_amdgcn_mfma_f32_16x16x32_bf16(
                afrag, bfrag, acc[mt], 0, 0, 0);
        }
        __syncthreads();
    }

    const int col = n0 + w * 16 + lane15;
    const int r4 = (lane >> 4) * 4;
#pragma unroll
    for (int mt = 0; mt < 4; ++mt)
#pragma unroll
        for (int j = 0; j < 4; ++j)
            P[(size_t)(mt * 16 + r4 + j) * DD + col] = acc[mt][j];
}

__global__ __launch_bounds__(256) void gemm_bf16_single(
    const u16* __restrict__ A, const u16* __restrict__ Wt,
    float* __restrict__ part, int kc)
{
    float* P = part + (size_t)blockIdx.y * 64 * DD;
    gemm_bf16_body(A, Wt, P, kc);
}

__global__ __launch_bounds__(256) void gemm_bf16_kv(
    const u16* __restrict__ A, const u16* __restrict__ Wkt,
    const u16* __restrict__ Wvt, float* __restrict__ p0,
    float* __restrict__ p1, int kc)
{
    const u16* Wt = blockIdx.z ? Wvt : Wkt;
    float* P = (blockIdx.z ? p1 : p0) + (size_t)blockIdx.y * 64 * DD;
    gemm_bf16_body(A, Wt, P, kc);
}

// [z; dz] @ Wq: partial layout [KS][128][2048]
__global__ __launch_bounds__(256) void gemm_bf16_q(
    const u16* __restrict__ zb, const u16* __restrict__ dzb,
    const u16* __restrict__ Wqt, float* __restrict__ part, int kc)
{
    const u16* A = blockIdx.z ? dzb : zb;
    float* P = part + ((size_t)blockIdx.y * 128 + blockIdx.z * 64) * DD;
    gemm_bf16_body(A, Wqt, P, kc);
}

// ---- epilogues (bf16 path)
__global__ __launch_bounds__(256) void ep_h(
    const float* __restrict__ p, const float* __restrict__ b1,
    u16* __restrict__ hb, int KS)
{
    int i = blockIdx.x * 256 + threadIdx.x;
    float s = b1[i & (DD - 1)];
    for (int ks = 0; ks < KS; ++ks) s += p[(size_t)ks * BD + i];
    hb[i] = f2b(tanhf(s));
}

__global__ __launch_bounds__(256) void ep_dz(
    const float* __restrict__ p, const float* __restrict__ b2,
    float* __restrict__ dz, u16* __restrict__ dzb, int KS)
{
    int i = blockIdx.x * 256 + threadIdx.x;
    float s = b2[i & (DD - 1)];
    for (int ks = 0; ks < KS; ++ks) s += p[(size_t)ks * BD + i];
    dz[i]  = s;
    dzb[i] = f2b(s);
}

__global__ __launch_bounds__(256) void ep_kv(
    const float* __restrict__ pk, const float* __restrict__ pv,
    const float* __restrict__ bk, const float* __restrict__ bv,
    float* __restrict__ dKo, float* __restrict__ vo, int KS)
{
    int i = blockIdx.x * 256 + threadIdx.x;
    int d = i & (DD - 1);
    float sk = 0.f, sv = 0.f;
    for (int ks = 0; ks < KS; ++ks) {
        sk += pk[(size_t)ks * BD + i];
        sv += pv[(size_t)ks * BD + i];
    }
    dKo[i] = expf(sk + bk[d]);
    vo[i]  = sv + bv[d];
}

__global__ __launch_bounds__(256) void ep_q_dq(
    const float* __restrict__ pq, const float* __restrict__ bq,
    float* __restrict__ qo, float* __restrict__ dqo, int KS)
{
    int i = blockIdx.x * 256 + threadIdx.x;
    int b = i >> 11, d = i & (DD - 1);
    float sq = 0.f, sd = 0.f;
    for (int ks = 0; ks < KS; ++ks) {
        const float* P = pq + (size_t)ks * (128 * DD);
        sq += P[(size_t)b * DD + d];
        sd += P[(size_t)(b + 64) * DD + d];
    }
    float bb = bq[d];
    float qv = expf(sq + bb);
    qo[i]  = qv;
    dqo[i] = qv * (sd + bb);
}

// ===========================================================================
// f32 fallback GEMM path (round-2 code, used only if d_ws is small)
// ===========================================================================
template<int MT>
__device__ __forceinline__ void gemm_body_f32(
    const float* __restrict__ A0, const float* __restrict__ A1,
    const float* __restrict__ W, float* __restrict__ part, int kc)
{
    constexpr int KC = 32;
    constexpr int RT = MT / 16;
    __shared__ float As[KC][MT];
    __shared__ float Ws[KC][64];

    const int t  = threadIdx.x;
    const int n0 = blockIdx.x * 64;
    const int k0 = blockIdx.y * kc;
    const int i  = t >> 4;
    const int j  = t & 15;

    float acc[RT][4];
#pragma unroll
    for (int r = 0; r < RT; ++r)
#pragma unroll
        for (int c = 0; c < 4; ++c) acc[r][c] = 0.f;

    for (int kk0 = 0; kk0 < kc; kk0 += KC) {
        {
            int kk = t >> 3;
            int nn = (t & 7) << 3;
            const float* s = W + (size_t)(k0 + kk0 + kk) * DD + n0 + nn;
            *(float4*)&Ws[kk][nn]     = *(const float4*)s;
            *(float4*)&Ws[kk][nn + 4] = *(const float4*)(s + 4);
        }
        if constexpr (MT == 64) {
            int m  = t & 63;
            int kb = (t >> 6) << 3;
            const float* s = A0 + (size_t)m * DD + k0 + kk0 + kb;
            float4 a0 = *(const float4*)s;
            float4 a1 = *(const float4*)(s + 4);
            As[kb+0][m] = a0.x; As[kb+1][m] = a0.y;
            As[kb+2][m] = a0.z; As[kb+3][m] = a0.w;
            As[kb+4][m] = a1.x; As[kb+5][m] = a1.y;
            As[kb+6][m] = a1.z; As[kb+7][m] = a1.w;
        } else {
            int m  = t & 127;
            int kb = (t >> 7) << 4;
            const float* base = (m < 64) ? (A0 + (size_t)m * DD)
                                         : (A1 + (size_t)(m - 64) * DD);
            const float* s = base + k0 + kk0 + kb;
#pragma unroll
            for (int p = 0; p < 4; ++p) {
                float4 av = *(const float4*)(s + p * 4);
                As[kb+p*4+0][m] = av.x; As[kb+p*4+1][m] = av.y;
                As[kb+p*4+2][m] = av.z; As[kb+p*4+3][m] = av.w;
            }
        }
        __syncthreads();
#pragma unroll
        for (int kk = 0; kk < KC; ++kk) {
            float4 wv = *(float4*)&Ws[kk][j << 2];
#pragma unroll
            for (int rq = 0; rq < RT / 4; ++rq) {
                float4 av = *(float4*)&As[kk][i * RT + rq * 4];
                acc[rq*4+0][0] = fmaf(av.x, wv.x, acc[rq*4+0][0]);
                acc[rq*4+0][1] = fmaf(av.x, wv.y, acc[rq*4+0][1]);
                acc[rq*4+0][2] = fmaf(av.x, wv.z, acc[rq*4+0][2]);
                acc[rq*4+0][3] = fmaf(av.x, wv.w, acc[rq*4+0][3]);
                acc[rq*4+1][0] = fmaf(av.y, wv.x, acc[rq*4+1][0]);
                acc[rq*4+1][1] = fmaf(av.y, wv.y, acc[rq*4+1][1]);
                acc[rq*4+1][2] = fmaf(av.y, wv.z, acc[rq*4+1][2]);
                acc[rq*4+1][3] = fmaf(av.y, wv.w, acc[rq*4+1][3]);
                acc[rq*4+2][0] = fmaf(av.z, wv.x, acc[rq*4+2][0]);
                acc[rq*4+2][1] = fmaf(av.z, wv.y, acc[rq*4+2][1]);
                acc[rq*4+2][2] = fmaf(av.z, wv.z, acc[rq*4+2][2]);
                acc[rq*4+2][3] = fmaf(av.z, wv.w, acc[rq*4+2][3]);
                acc[rq*4+3][0] = fmaf(av.w, wv.x, acc[rq*4+3][0]);
                acc[rq*4+3][1] = fmaf(av.w, wv.y, acc[rq*4+3][1]);
                acc[rq*4+3][2] = fmaf(av.w, wv.z, acc[rq*4+3][2]);
                acc[rq*4+3][3] = fmaf(av.w, wv.w, acc[rq*4+3][3]);
            }
        }
        __syncthreads();
    }

    float* P = part + (size_t)blockIdx.y * MT * DD + n0 + (j << 2);
#pragma unroll
    for (int r = 0; r < RT; ++r)
        *(float4*)&P[(size_t)(i * RT + r) * DD] =
            make_float4(acc[r][0], acc[r][1], acc[r][2], acc[r][3]);
}

__global__ __launch_bounds__(256) void gemm64(
    const float* __restrict__ A, const float* __restrict__ W,
    float* __restrict__ part, int kc)
{ gemm_body_f32<64>(A, A, W, part, kc); }

__global__ __launch_bounds__(256) void gemm64_z2(
    const float* __restrict__ A,
    const float* __restrict__ W0, const float* __restrict__ W1,
    float* __restrict__ p0, float* __restrict__ p1, int kc)
{
    const float* W = blockIdx.z ? W1 : W0;
    float*       P = blockIdx.z ? p1 : p0;
    gemm_body_f32<64>(A, A, W, P, kc);
}

__global__ __launch_bounds__(256) void gemm128(
    const float* __restrict__ A0, const float* __restrict__ A1,
    const float* __restrict__ W, float* __restrict__ part, int kc)
{ gemm_body_f32<128>(A0, A1, W, part, kc); }

__global__ __launch_bounds__(256) void epilogue_f32(
    const float* __restrict__ part, const float* __restrict__ bias,
    float* __restrict__ out, int act, int KS)
{
    int i = blockIdx.x * 256 + threadIdx.x;
    float s = bias[i & (DD - 1)];
    for (int ks = 0; ks < KS; ++ks) s += part[(size_t)ks * BD + i];
    if (act == 1) s = tanhf(s);
    out[i] = s;
}

// ===========================================================================
// shared tail kernels
// ===========================================================================
__global__ __launch_bounds__(256) void reduce_a_da(
    const float* __restrict__ q, const float* __restrict__ dK,
    const float* __restrict__ dq, const float* __restrict__ Kin,
    float* __restrict__ a_ws, float* __restrict__ da_out)
{
    int b = blockIdx.x;
    int t = threadIdx.x;
    const float* qb  = q   + (size_t)b * DD;
    const float* dKb = dK  + (size_t)b * DD;
    const float* dqb = dq  + (size_t)b * DD;
    const float* Kb  = Kin + (size_t)b * DD;

    float s1 = 0.f, s2 = 0.f;
    for (int i = t; i < DD; i += 256) {
        s1 = fmaf(qb[i],  dKb[i], s1);
        s2 = fmaf(dqb[i], Kb[i],  s2);
    }
#pragma unroll
    for (int off = 32; off; off >>= 1) {
        s1 += __shfl_down(s1, off);
        s2 += __shfl_down(s2, off);
    }
    __shared__ float r1[4], r2[4];
    if ((t & 63) == 0) { r1[t >> 6] = s1; r2[t >> 6] = s2; }
    __syncthreads();
    if (t == 0) {
        float a  = r1[0] + r1[1] + r1[2] + r1[3];
        float k2 = r2[0] + r2[1] + r2[2] + r2[3];
        a_ws[b]   = a;
        da_out[b] = a + k2;
    }
}

__global__ __launch_bounds__(256) void fused_dv_dc(
    const float* __restrict__ V, const float* __restrict__ v,
    const float* __restrict__ dK, const float* __restrict__ dq,
    const float* __restrict__ a, float* __restrict__ dV,
    float* __restrict__ dc)
{
    int b     = blockIdx.x >> 5;
    int chunk = blockIdx.x & 31;
    int wave  = threadIdx.x >> 6;
    int lane  = threadIdx.x & 63;

    const f4* dK4 = (const f4*)(dK + ((size_t)b << 11));
    const f4* dq4 = (const f4*)(dq + ((size_t)b << 11));
    f4 dKr[8], dqr[8];
#pragma unroll
    for (int u = 0; u < 8; ++u) {
        dKr[u] = dK4[u * 64 + lane];
        dqr[u] = dq4[u * 64 + lane];
    }
    float ab = a[b];
    int row0 = chunk * 64 + wave * 16;

    for (int g = 0; g < 4; ++g) {
        float dot[4];
#pragma unroll
        for (int r2 = 0; r2 < 4; ++r2) {
            int row = row0 + g * 4 + r2;
            size_t off = ((size_t)((b << 11) | row)) << 11;
            const f4* V4  = (const f4*)(V  + off);
            f4*       dV4 = (f4*)(dV + off);
            float vr = v[((size_t)b << 11) + row];
            float d  = 0.f;
#pragma unroll
            for (int u = 0; u < 8; ++u) {
                f4 Vv = __builtin_nontemporal_load(&V4[u * 64 + lane]);
                d += Vv[0] * dqr[u][0] + Vv[1] * dqr[u][1]
                   + Vv[2] * dqr[u][2] + Vv[3] * dqr[u][3];
                f4 o = vr * dKr[u];
                __builtin_nontemporal_store(o, &dV4[u * 64 + lane]);
            }
            dot[r2] = d;
        }
#pragma unroll
        for (int r2 = 0; r2 < 4; ++r2) {
            float d = dot[r2];
#pragma unroll
            for (int s = 32; s; s >>= 1) d += __shfl_down(d, s);
            if (lane == 0) {
                int row = row0 + g * 4 + r2;
                dc[((size_t)b << 11) + row] =
                    v[((size_t)b << 11) + row] * ab + d;
            }
        }
    }
}

// ===========================================================================
extern "C" void kernel_launch(void* const* d_in, const int* in_sizes, int n_in,
                              void* d_out, int out_size, void* d_ws, size_t ws_size,
                              hipStream_t stream)
{
    const float* z   = (const float*)d_in[1];
    const float* Kin = (const float*)d_in[2];
    const float* Vin = (const float*)d_in[3];
    const float* Wq  = (const float*)d_in[4];
    const float* bq  = (const float*)d_in[5];
    const float* Wk  = (const float*)d_in[6];
    const float* bk  = (const float*)d_in[7];
    const float* Wv  = (const float*)d_in[8];
    const float* bv  = (const float*)d_in[9];
    const float* W1  = (const float*)d_in[10];
    const float* b1  = (const float*)d_in[11];
    const float* W2  = (const float*)d_in[12];
    const float* b2  = (const float*)d_in[13];

    float* out   = (float*)d_out;
    float* o_dz  = out;
    float* o_da  = out + BD;
    float* o_dc  = out + BD + BB;
    float* o_dK  = out + 2 * BD + BB;
    float* o_dV  = out + 3 * BD + BB;

    float* ws    = (float*)d_ws;
    float* ws_v  = ws;
    float* ws_q  = ws + BD;
    float* ws_dq = ws + 2 * BD;
    float* ws_a  = ws + 3 * BD;          // 64
    float* ws_h  = ws + 3 * BD + 64;     // fallback only
    u16*   zb    = (u16*)(ws + 4 * BD + 64);
    u16*   hb    = zb + BD;
    u16*   dzb   = hb + BD;
    u16*   wt    = dzb + BD;             // 5 * WN u16
    float* poolb = (float*)(wt + 5ull * WN);

    // floats consumed before pool in bf16 path:
    const size_t pre_fl = 4ull * BD + 64 + (3ull * BD + 5ull * WN) / 2;

    int KS = 0;
    for (int ks = 16; ks >= 4; ks >>= 1)
        if ((pre_fl + 2ull * ks * BD) * 4ull <= ws_size) { KS = ks; break; }

    dim3 blk(256);
    dim3 gE(BD / 256);

    if (KS) {
        // ------------------- bf16 MFMA path -------------------
        int kc = DD / KS;
        float* p0 = poolb;
        float* p1 = poolb + (size_t)KS * BD;

        dim3 gW(32, 32, 5);
        dim3 gG(32, KS);
        dim3 gG2(32, KS, 2);

        wconv<<<gW, blk, 0, stream>>>(W1, W2, Wk, Wv, Wq, wt);
        zconv<<<dim3(BD / 1024), blk, 0, stream>>>(z, zb);

        u16* W1t = wt;
        u16* W2t = wt + 1ull * WN;
        u16* Wkt = wt + 2ull * WN;
        u16* Wvt = wt + 3ull * WN;
        u16* Wqt = wt + 4ull * WN;

        // 1) h = tanh(z @ W1 + b1)   (bf16 out only)
        gemm_bf16_single<<<gG, blk, 0, stream>>>(zb, W1t, p0, kc);
        ep_h<<<gE, blk, 0, stream>>>(p0, b1, hb, KS);

        // 2) dz = h @ W2 + b2        (f32 + bf16)
        gemm_bf16_single<<<gG, blk, 0, stream>>>(hb, W2t, p0, kc);
        ep_dz<<<gE, blk, 0, stream>>>(p0, b2, o_dz, dzb, KS);

        // 3) dK = exp(z@Wk+bk); v = z@Wv+bv
        gemm_bf16_kv<<<gG2, blk, 0, stream>>>(zb, Wkt, Wvt, p0, p1, kc);
        ep_kv<<<gE, blk, 0, stream>>>(p0, p1, bk, bv, o_dK, ws_v, KS);

        // 4) [z; dz] @ Wq -> q, dq
        gemm_bf16_q<<<gG2, blk, 0, stream>>>(zb, dzb, Wqt, p0, kc);
        ep_q_dq<<<gE, blk, 0, stream>>>(p0, bq, ws_q, ws_dq, KS);
    } else {
        // ------------------- f32 fallback path -------------------
        // round-2 layout: pool right after ws_h
        float* pool = ws + 4 * BD + 64;
        int KSf = 16;
        while (KSf > 1 &&
               ((size_t)(4 * BD + 64) + 2ull * KSf * BD) * 4ull > ws_size)
            KSf >>= 1;
        int kc = DD / KSf;
        float* p0 = pool;
        float* p1 = pool + (size_t)KSf * BD;

        dim3 gG(DD / 64, KSf);
        dim3 gG2(DD / 64, KSf, 2);

        gemm64<<<gG, blk, 0, stream>>>(z, W1, p0, kc);
        epilogue_f32<<<gE, blk, 0, stream>>>(p0, b1, ws_h, 1, KSf);

        gemm64<<<gG, blk, 0, stream>>>(ws_h, W2, p0, kc);
        epilogue_f32<<<gE, blk, 0, stream>>>(p0, b2, o_dz, 0, KSf);

        gemm64_z2<<<gG2, blk, 0, stream>>>(z, Wk, Wv, p0, p1, kc);
        ep_kv<<<gE, blk, 0, stream>>>(p0, p1, bk, bv, o_dK, ws_v, KSf);

        gemm128<<<gG, blk, 0, stream>>>(z, o_dz, Wq, p0, kc);
        ep_q_dq<<<gE, blk, 0, stream>>>(p0, bq, ws_q, ws_dq, KSf);
    }

    // 5) a = q . dK ; da = a + dq . K
    reduce_a_da<<<dim3(BB), blk, 0, stream>>>(ws_q, o_dK, ws_dq, Kin, ws_a, o_da);

    // 6) dV = outer(v, dK); dc = v*a + V @ dq
    fused_dv_dc<<<dim3(BB * 32), blk, 0, stream>>>(Vin, ws_v, o_dK, ws_dq, ws_a,
                                                   o_dV, o_dc);
}